// Round 7
// baseline (470.261 us; speedup 1.0000x reference)
//
#include <hip/hip_runtime.h>

#define N_NODES 50000
#define N_EDGES 800000
#define TOT_E   (N_EDGES + N_NODES)
#define EPS     1e-5f
#define SCAN_NB 196                      // ceil(N_NODES/256)

typedef unsigned short u16;
typedef short v8s __attribute__((ext_vector_type(8)));
typedef float v4f __attribute__((ext_vector_type(4)));

// workspace byte offsets
#define WS_W1H    0          // [64 n][32 k] bf16 hi plane   4096 B
#define WS_W1L    4096       // lo plane                     4096 B
#define WS_W2H    8192       // [64 n][64 k]                 8192 B
#define WS_W2L    16384
#define WS_W3H    24576      // [128 n][64 k]               16384 B
#define WS_W3L    40960
#define WS_B1F    57344      // 64 f32
#define WS_B2F    57600
#define WS_B3F    57856      // 128 f32
#define WS_BSUM   58368      // SCAN_NB ints (padded to 1024)
#define WS_CURSOR 59392      // N_NODES ints
#define WS_EID    259392     // TOT_E ints

__device__ __forceinline__ unsigned rne_bf16(float f) {
    unsigned u = __float_as_uint(f);
    return (u + 0x7fffu + ((u >> 16) & 1u)) >> 16;
}

#define MFMA3(acc, ah, al, bh, bl)                                           \
    acc = __builtin_amdgcn_mfma_f32_16x16x32_bf16(ah, bh, acc, 0, 0, 0);     \
    acc = __builtin_amdgcn_mfma_f32_16x16x32_bf16(ah, bl, acc, 0, 0, 0);     \
    acc = __builtin_amdgcn_mfma_f32_16x16x32_bf16(al, bh, acc, 0, 0, 0);

__global__ void fold_kernel(
    const float* __restrict__ W1, const float* __restrict__ b1,
    const float* __restrict__ g1, const float* __restrict__ be1,
    const float* __restrict__ m1, const float* __restrict__ v1,
    const float* __restrict__ W2, const float* __restrict__ b2,
    const float* __restrict__ g2, const float* __restrict__ be2,
    const float* __restrict__ m2, const float* __restrict__ v2,
    const float* __restrict__ W3, const float* __restrict__ b3,
    const float* __restrict__ g3, const float* __restrict__ be3,
    const float* __restrict__ m3, const float* __restrict__ v3,
    u16* __restrict__ w1h, u16* __restrict__ w1l,
    u16* __restrict__ w2h, u16* __restrict__ w2l,
    u16* __restrict__ w3h, u16* __restrict__ w3l,
    float* __restrict__ b1f, float* __restrict__ b2f, float* __restrict__ b3f)
{
    int t = blockIdx.x * blockDim.x + threadIdx.x;
    float val = 0.f;
    u16 *ph = nullptr, *pl = nullptr;
    int idx = 0;
    if (t < 2048) {                       // W1 [n][32k], k>=6 zero
        int n = t >> 5, k = t & 31;
        float s = g1[n] * rsqrtf(v1[n] + EPS);
        val = (k < 6) ? W1[k * 64 + n] * s : 0.f;
        ph = w1h; pl = w1l; idx = t;
    } else if (t < 6144) {                // W2 [n][64k]
        int i = t - 2048; int n = i >> 6, k = i & 63;
        float s = g2[n] * rsqrtf(v2[n] + EPS);
        val = W2[k * 64 + n] * s;
        ph = w2h; pl = w2l; idx = i;
    } else if (t < 14336) {               // W3 [n][64k]
        int i = t - 6144; int n = i >> 6, k = i & 63;
        float s = g3[n] * rsqrtf(v3[n] + EPS);
        val = W3[k * 128 + n] * s;
        ph = w3h; pl = w3l; idx = i;
    } else if (t < 14592) {               // biases
        int i = t - 14336;
        if (i < 64) {
            float s = g1[i] * rsqrtf(v1[i] + EPS);
            b1f[i] = (b1[i] - m1[i]) * s + be1[i];
        } else if (i < 128) {
            int j = i - 64;
            float s = g2[j] * rsqrtf(v2[j] + EPS);
            b2f[j] = (b2[j] - m2[j]) * s + be2[j];
        } else {
            int j = i - 128;
            float s = g3[j] * rsqrtf(v3[j] + EPS);
            b3f[j] = (b3[j] - m3[j]) * s + be3[j];
        }
        return;
    } else return;
    unsigned hi = rne_bf16(val);
    unsigned lo = rne_bf16(val - __uint_as_float(hi << 16));
    ph[idx] = (u16)hi;
    pl[idx] = (u16)lo;
}

// cursor = 1 (self loop) and out = -inf in one pass
__global__ void init_kernel(int* __restrict__ cursor, uint4* __restrict__ out4) {
    int i = blockIdx.x * 256 + threadIdx.x;
    if (i < N_NODES) cursor[i] = 1;
    if (i < (N_NODES * 128) / 4)
        out4[i] = make_uint4(0xFF800000u, 0xFF800000u, 0xFF800000u, 0xFF800000u);
}

__global__ void hist_kernel(const int* __restrict__ ei, int* __restrict__ cursor) {
    int e = blockIdx.x * 256 + threadIdx.x;
    if (e < N_EDGES) atomicAdd(&cursor[ei[N_EDGES + e]], 1);
}

// multi-block scan: A) per-block exclusive scan + block sums
__global__ void scanA_kernel(int* __restrict__ cursor, int* __restrict__ bsum) {
    __shared__ int sh[256];
    const int tid = threadIdx.x;
    int i = blockIdx.x * 256 + tid;
    int c = (i < N_NODES) ? cursor[i] : 0;
    sh[tid] = c;
    __syncthreads();
    int v = c;
    for (int off = 1; off < 256; off <<= 1) {
        int t = (tid >= off) ? sh[tid - off] : 0;
        __syncthreads();
        v += t;
        sh[tid] = v;
        __syncthreads();
    }
    if (i < N_NODES) cursor[i] = v - c;           // exclusive within block
    if (tid == 255) bsum[blockIdx.x] = v;         // block total
}

// B) exclusive scan of the block sums (single small block)
__global__ void scanB_kernel(int* __restrict__ bsum) {
    __shared__ int sh[256];
    const int tid = threadIdx.x;
    int c = (tid < SCAN_NB) ? bsum[tid] : 0;
    sh[tid] = c;
    __syncthreads();
    int v = c;
    for (int off = 1; off < 256; off <<= 1) {
        int t = (tid >= off) ? sh[tid - off] : 0;
        __syncthreads();
        v += t;
        sh[tid] = v;
        __syncthreads();
    }
    if (tid < SCAN_NB) bsum[tid] = v - c;
}

// C) add block offsets
__global__ void scanC_kernel(int* __restrict__ cursor, const int* __restrict__ bsum) {
    int i = blockIdx.x * 256 + threadIdx.x;
    if (i < N_NODES) cursor[i] += bsum[blockIdx.x];
}

__global__ void scatter_kernel(const int* __restrict__ ei, int* __restrict__ cursor,
                               int* __restrict__ eid) {
    int e = blockIdx.x * 256 + threadIdx.x;
    if (e >= TOT_E) return;
    int d = (e < N_EDGES) ? ei[N_EDGES + e] : (e - N_EDGES);
    int p = atomicAdd(&cursor[d], 1);
    eid[p] = e;
}

// 2 waves/block co-op on 64 edges, split by output features.
// LDS 16KB: bf16 hi plane [64][64] @0, lo plane @8192; reused as 2x 8KB f32
// epilogue stage regions. All row-major accesses swizzled byte^=((row&7)<<4).
__global__ __launch_bounds__(128, 4) void gather_kernel(
    const float* __restrict__ x, const float* __restrict__ pos,
    const int* __restrict__ ei, const int* __restrict__ eid,
    const u16* __restrict__ w1h, const u16* __restrict__ w1l,
    const u16* __restrict__ w2h, const u16* __restrict__ w2l,
    const u16* __restrict__ w3h, const u16* __restrict__ w3l,
    const float* __restrict__ b1f, const float* __restrict__ b2f,
    const float* __restrict__ b3f, float* __restrict__ out)
{
    __shared__ uint4 smem4[1024];            // 16384 B
    char* smem = (char*)smem4;

    const int tid = threadIdx.x;
    const int wid = tid >> 6;
    const int lane = tid & 63;
    const int l15 = lane & 15, g = lane >> 4;
    const int e = blockIdx.x * 64 + lane;
    const bool active = e < TOT_E;

    int src = 0, dst = 0;
    if (active) {
        int id = eid[e];
        if (id < N_EDGES) { src = ei[id]; dst = ei[N_EDGES + id]; }
        else              { src = dst = id - N_EDGES; }
    }
    const int nid = active ? dst : (-1 - lane);   // unique negatives in tail

    // full-exec-mask shuffles only (round-4 lesson)
    const int np1 = __shfl_down(nid, 1);
    const bool seg_last = (lane == 63) || (np1 != nid);
    const unsigned long long segmask = __ballot(seg_last);

    float f0 = x[src * 3 + 0];
    float f1 = x[src * 3 + 1];
    float f2 = x[src * 3 + 2];
    float f3 = pos[src * 3 + 0] - pos[dst * 3 + 0];
    float f4 = pos[src * 3 + 1] - pos[dst * 3 + 1];
    float f5 = pos[src * 3 + 2] - pos[dst * 3 + 2];

    // pack f hi/lo pairs: u*0 = [k0|k1], u*1 = [k2|k3], u*2 = [k4|k5]
    unsigned h0 = rne_bf16(f0), h1 = rne_bf16(f1), h2 = rne_bf16(f2);
    unsigned h3 = rne_bf16(f3), h4 = rne_bf16(f4), h5 = rne_bf16(f5);
    unsigned l0 = rne_bf16(f0 - __uint_as_float(h0 << 16));
    unsigned l1 = rne_bf16(f1 - __uint_as_float(h1 << 16));
    unsigned l2 = rne_bf16(f2 - __uint_as_float(h2 << 16));
    unsigned l3 = rne_bf16(f3 - __uint_as_float(h3 << 16));
    unsigned l4 = rne_bf16(f4 - __uint_as_float(h4 << 16));
    unsigned l5 = rne_bf16(f5 - __uint_as_float(h5 << 16));
    unsigned uh0 = h0 | (h1 << 16), uh1 = h2 | (h3 << 16), uh2 = h4 | (h5 << 16);
    unsigned ul0 = l0 | (l1 << 16), ul1 = l2 | (l3 << 16), ul2 = l4 | (l5 << 16);

    // L1 A-frags via bpermute (edge 16tm+l15's features; g>0 lanes are k>=8 -> 0)
    v8s a1h[4], a1l[4];
#pragma unroll
    for (int tm = 0; tm < 4; ++tm) {
        int bidx = (16 * tm + l15) * 4;
        unsigned p0 = (unsigned)__builtin_amdgcn_ds_bpermute(bidx, (int)uh0);
        unsigned p1 = (unsigned)__builtin_amdgcn_ds_bpermute(bidx, (int)uh1);
        unsigned p2 = (unsigned)__builtin_amdgcn_ds_bpermute(bidx, (int)uh2);
        unsigned q0 = (unsigned)__builtin_amdgcn_ds_bpermute(bidx, (int)ul0);
        unsigned q1 = (unsigned)__builtin_amdgcn_ds_bpermute(bidx, (int)ul1);
        unsigned q2 = (unsigned)__builtin_amdgcn_ds_bpermute(bidx, (int)ul2);
        if (g != 0) { p0 = p1 = p2 = q0 = q1 = q2 = 0u; }
        uint4 th = make_uint4(p0, p1, p2, 0u);
        uint4 tl = make_uint4(q0, q1, q2, 0u);
        a1h[tm] = __builtin_bit_cast(v8s, th);
        a1l[tm] = __builtin_bit_cast(v8s, tl);
    }

    // ---- layer 1 (wave handles tn = 2*wid + t2)
    v4f acc[2][4];
#pragma unroll
    for (int t2 = 0; t2 < 2; ++t2) {
        int tn = 2 * wid + t2;
        float bv = b1f[16 * tn + l15];
#pragma unroll
        for (int tm = 0; tm < 4; ++tm) acc[t2][tm] = (v4f){bv, bv, bv, bv};
    }
#pragma unroll
    for (int t2 = 0; t2 < 2; ++t2) {
        int tn = 2 * wid + t2;
        v8s bh = *(const v8s*)&w1h[(16 * tn + l15) * 32 + g * 8];
        v8s bl = *(const v8s*)&w1l[(16 * tn + l15) * 32 + g * 8];
#pragma unroll
        for (int tm = 0; tm < 4; ++tm) { MFMA3(acc[t2][tm], a1h[tm], a1l[tm], bh, bl) }
    }
    // relu + split + write H1 planes (this wave's cols)
#pragma unroll
    for (int t2 = 0; t2 < 2; ++t2)
#pragma unroll
        for (int tm = 0; tm < 4; ++tm)
#pragma unroll
            for (int r = 0; r < 4; ++r) {
                int tn = 2 * wid + t2;
                int row = 16 * tm + 4 * g + r, col = 16 * tn + l15;
                float v = fmaxf(acc[t2][tm][r], 0.f);
                unsigned hi = rne_bf16(v);
                unsigned lo = rne_bf16(v - __uint_as_float(hi << 16));
                int off = row * 128 + ((col * 2) ^ ((row & 7) << 4));
                *(u16*)(smem + off) = (u16)hi;
                *(u16*)(smem + 8192 + off) = (u16)lo;
            }
    __syncthreads();

    // ---- read H1 A-frags (both waves read all)
    v8s ah[4][2], al[4][2];
#pragma unroll
    for (int tm = 0; tm < 4; ++tm)
#pragma unroll
        for (int tk = 0; tk < 2; ++tk) {
            int row = 16 * tm + l15;
            int off = row * 128 + ((tk * 64 + g * 16) ^ ((row & 7) << 4));
            ah[tm][tk] = *(const v8s*)(smem + off);
            al[tm][tk] = *(const v8s*)(smem + 8192 + off);
        }
    __syncthreads();   // reads complete before H2 overwrite

    // ---- layer 2
#pragma unroll
    for (int t2 = 0; t2 < 2; ++t2) {
        int tn = 2 * wid + t2;
        float bv = b2f[16 * tn + l15];
#pragma unroll
        for (int tm = 0; tm < 4; ++tm) acc[t2][tm] = (v4f){bv, bv, bv, bv};
    }
#pragma unroll
    for (int t2 = 0; t2 < 2; ++t2)
#pragma unroll
        for (int tk = 0; tk < 2; ++tk) {
            int tn = 2 * wid + t2;
            v8s bh = *(const v8s*)&w2h[(16 * tn + l15) * 64 + tk * 32 + g * 8];
            v8s bl = *(const v8s*)&w2l[(16 * tn + l15) * 64 + tk * 32 + g * 8];
#pragma unroll
            for (int tm = 0; tm < 4; ++tm) { MFMA3(acc[t2][tm], ah[tm][tk], al[tm][tk], bh, bl) }
        }
#pragma unroll
    for (int t2 = 0; t2 < 2; ++t2)
#pragma unroll
        for (int tm = 0; tm < 4; ++tm)
#pragma unroll
            for (int r = 0; r < 4; ++r) {
                int tn = 2 * wid + t2;
                int row = 16 * tm + 4 * g + r, col = 16 * tn + l15;
                float v = fmaxf(acc[t2][tm][r], 0.f);
                unsigned hi = rne_bf16(v);
                unsigned lo = rne_bf16(v - __uint_as_float(hi << 16));
                int off = row * 128 + ((col * 2) ^ ((row & 7) << 4));
                *(u16*)(smem + off) = (u16)hi;
                *(u16*)(smem + 8192 + off) = (u16)lo;
            }
    __syncthreads();

    // ---- read H2 A-frags
#pragma unroll
    for (int tm = 0; tm < 4; ++tm)
#pragma unroll
        for (int tk = 0; tk < 2; ++tk) {
            int row = 16 * tm + l15;
            int off = row * 128 + ((tk * 64 + g * 16) ^ ((row & 7) << 4));
            ah[tm][tk] = *(const v8s*)(smem + off);
            al[tm][tk] = *(const v8s*)(smem + 8192 + off);
        }
    __syncthreads();   // reads complete before epilogue-stage overwrite

    // ---- layer 3: wave wid owns out-half h=wid; two tn-pair phases.
    // Each wave stages its phase (64 edges x 32 cols f32) into region wid*8192,
    // then both waves walk: wave w edges [32w,32w+32), lanes = 64 feature cols.
#pragma unroll
    for (int ph = 0; ph < 2; ++ph) {
        v4f a3[2][4];
#pragma unroll
        for (int t2 = 0; t2 < 2; ++t2) {
            int tnq = 2 * ph + t2;
            float bv = b3f[64 * wid + 16 * tnq + l15];
#pragma unroll
            for (int tm = 0; tm < 4; ++tm) a3[t2][tm] = (v4f){bv, bv, bv, bv};
        }
#pragma unroll
        for (int t2 = 0; t2 < 2; ++t2)
#pragma unroll
            for (int tk = 0; tk < 2; ++tk) {
                int tnq = 2 * ph + t2;
                int nrow = 16 * (4 * wid + tnq) + l15;
                v8s bh = *(const v8s*)&w3h[nrow * 64 + tk * 32 + g * 8];
                v8s bl = *(const v8s*)&w3l[nrow * 64 + tk * 32 + g * 8];
#pragma unroll
                for (int tm = 0; tm < 4; ++tm) { MFMA3(a3[t2][tm], ah[tm][tk], al[tm][tk], bh, bl) }
            }
        // stage f32 into own region: rows 128B (32 cols)
#pragma unroll
        for (int t2 = 0; t2 < 2; ++t2)
#pragma unroll
            for (int tm = 0; tm < 4; ++tm)
#pragma unroll
                for (int r = 0; r < 4; ++r) {
                    int row = 16 * tm + 4 * g + r;
                    int c32 = 16 * t2 + l15;
                    int off = wid * 8192 + row * 128 + ((c32 * 4) ^ ((row & 7) << 4));
                    *(float*)(smem + off) = a3[t2][tm][r];
                }
        __syncthreads();

        // walk: lane<32 -> h0 region (out cols ph*32+l31), lane>=32 -> h1 region
        {
            const int reg = lane >> 5, l31 = lane & 31;
            const int ocol = reg * 64 + ph * 32 + l31;
            float runmax = -__builtin_inff();
            bool first = true;
            const int ebeg = 32 * wid;
#pragma unroll
            for (int i = 0; i < 32; ++i) {
                int e2 = ebeg + i;
                int off = reg * 8192 + e2 * 128 + ((l31 * 4) ^ ((e2 & 7) << 4));
                float val = *(const float*)(smem + off);
                runmax = fmaxf(runmax, val);
                bool segbit = (segmask >> e2) & 1ull;
                bool lastit = (i == 31);
                if (segbit || lastit) {
                    int n = __builtin_amdgcn_readlane(nid, e2);
                    if (n >= 0) {
                        float* op = out + (size_t)n * 128 + ocol;
                        // first/last flush of subrange may span wave/block bounds
                        if (first || lastit) atomicMax(op, runmax);
                        else *op = runmax;
                    }
                    first = false;
                    runmax = -__builtin_inff();
                }
            }
        }
        __syncthreads();
    }
}

extern "C" void kernel_launch(void* const* d_in, const int* in_sizes, int n_in,
                              void* d_out, int out_size, void* d_ws, size_t ws_size,
                              hipStream_t stream) {
    const float* x   = (const float*)d_in[0];
    const float* pos = (const float*)d_in[1];
    const float* W1  = (const float*)d_in[2];
    const float* b1  = (const float*)d_in[3];
    const float* g1  = (const float*)d_in[4];
    const float* be1 = (const float*)d_in[5];
    const float* m1  = (const float*)d_in[6];
    const float* v1  = (const float*)d_in[7];
    const float* W2  = (const float*)d_in[8];
    const float* b2  = (const float*)d_in[9];
    const float* g2  = (const float*)d_in[10];
    const float* be2 = (const float*)d_in[11];
    const float* m2  = (const float*)d_in[12];
    const float* v2  = (const float*)d_in[13];
    const float* W3  = (const float*)d_in[14];
    const float* b3  = (const float*)d_in[15];
    const float* g3  = (const float*)d_in[16];
    const float* be3 = (const float*)d_in[17];
    const float* m3  = (const float*)d_in[18];
    const float* v3  = (const float*)d_in[19];
    const int*   ei  = (const int*)d_in[20];

    char* ws = (char*)d_ws;
    u16* w1h = (u16*)(ws + WS_W1H);
    u16* w1l = (u16*)(ws + WS_W1L);
    u16* w2h = (u16*)(ws + WS_W2H);
    u16* w2l = (u16*)(ws + WS_W2L);
    u16* w3h = (u16*)(ws + WS_W3H);
    u16* w3l = (u16*)(ws + WS_W3L);
    float* b1f = (float*)(ws + WS_B1F);
    float* b2f = (float*)(ws + WS_B2F);
    float* b3f = (float*)(ws + WS_B3F);
    int* bsum   = (int*)(ws + WS_BSUM);
    int* cursor = (int*)(ws + WS_CURSOR);
    int* eid    = (int*)(ws + WS_EID);
    float* outf = (float*)d_out;

    fold_kernel<<<57, 256, 0, stream>>>(
        W1, b1, g1, be1, m1, v1, W2, b2, g2, be2, m2, v2,
        W3, b3, g3, be3, m3, v3, w1h, w1l, w2h, w2l, w3h, w3l, b1f, b2f, b3f);

    init_kernel<<<(N_NODES * 128 / 4 + 255) / 256, 256, 0, stream>>>(
        cursor, (uint4*)d_out);

    hist_kernel<<<(N_EDGES + 255) / 256, 256, 0, stream>>>(ei, cursor);
    scanA_kernel<<<SCAN_NB, 256, 0, stream>>>(cursor, bsum);
    scanB_kernel<<<1, 256, 0, stream>>>(bsum);
    scanC_kernel<<<SCAN_NB, 256, 0, stream>>>(cursor, bsum);
    scatter_kernel<<<(TOT_E + 255) / 256, 256, 0, stream>>>(ei, cursor, eid);

    gather_kernel<<<(TOT_E + 63) / 64, 128, 0, stream>>>(
        x, pos, ei, eid, w1h, w1l, w2h, w2l, w3h, w3l, b1f, b2f, b3f, outf);
}

// Round 8
// 274.091 us; speedup vs baseline: 1.7157x; 1.7157x over previous
//
#include <hip/hip_runtime.h>

#define N_NODES 50000
#define N_EDGES 800000
#define TOT_E   (N_EDGES + N_NODES)
#define EPS     1e-5f
#define SCAN_NB 196                      // ceil(N_NODES/256)

typedef unsigned short u16;
typedef short v8s __attribute__((ext_vector_type(8)));
typedef float v4f __attribute__((ext_vector_type(4)));

// workspace byte offsets
#define WS_W1H    0          // [64 n][32 k] bf16 hi plane   4096 B
#define WS_W1L    4096       // lo plane                     4096 B
#define WS_W2H    8192       // [64 n][64 k]                 8192 B
#define WS_W2L    16384
#define WS_W3H    24576      // [128 n][64 k]               16384 B
#define WS_W3L    40960
#define WS_B1F    57344      // 64 f32
#define WS_B2F    57600
#define WS_B3F    57856      // 128 f32
#define WS_BSUM   58368      // SCAN_NB ints (padded to 1024)
#define WS_CURSOR 59392      // N_NODES ints
#define WS_EID    259392     // TOT_E ints

__device__ __forceinline__ unsigned rne_bf16(float f) {
    unsigned u = __float_as_uint(f);
    return (u + 0x7fffu + ((u >> 16) & 1u)) >> 16;
}

#define MFMA3(acc, ah, al, bh, bl)                                           \
    acc = __builtin_amdgcn_mfma_f32_16x16x32_bf16(ah, bh, acc, 0, 0, 0);     \
    acc = __builtin_amdgcn_mfma_f32_16x16x32_bf16(ah, bl, acc, 0, 0, 0);     \
    acc = __builtin_amdgcn_mfma_f32_16x16x32_bf16(al, bh, acc, 0, 0, 0);

__global__ void fold_kernel(
    const float* __restrict__ W1, const float* __restrict__ b1,
    const float* __restrict__ g1, const float* __restrict__ be1,
    const float* __restrict__ m1, const float* __restrict__ v1,
    const float* __restrict__ W2, const float* __restrict__ b2,
    const float* __restrict__ g2, const float* __restrict__ be2,
    const float* __restrict__ m2, const float* __restrict__ v2,
    const float* __restrict__ W3, const float* __restrict__ b3,
    const float* __restrict__ g3, const float* __restrict__ be3,
    const float* __restrict__ m3, const float* __restrict__ v3,
    u16* __restrict__ w1h, u16* __restrict__ w1l,
    u16* __restrict__ w2h, u16* __restrict__ w2l,
    u16* __restrict__ w3h, u16* __restrict__ w3l,
    float* __restrict__ b1f, float* __restrict__ b2f, float* __restrict__ b3f)
{
    int t = blockIdx.x * blockDim.x + threadIdx.x;
    float val = 0.f;
    u16 *ph = nullptr, *pl = nullptr;
    int idx = 0;
    if (t < 2048) {                       // W1 [n][32k], k>=6 zero
        int n = t >> 5, k = t & 31;
        float s = g1[n] * rsqrtf(v1[n] + EPS);
        val = (k < 6) ? W1[k * 64 + n] * s : 0.f;
        ph = w1h; pl = w1l; idx = t;
    } else if (t < 6144) {                // W2 [n][64k]
        int i = t - 2048; int n = i >> 6, k = i & 63;
        float s = g2[n] * rsqrtf(v2[n] + EPS);
        val = W2[k * 64 + n] * s;
        ph = w2h; pl = w2l; idx = i;
    } else if (t < 14336) {               // W3 [n][64k]
        int i = t - 6144; int n = i >> 6, k = i & 63;
        float s = g3[n] * rsqrtf(v3[n] + EPS);
        val = W3[k * 128 + n] * s;
        ph = w3h; pl = w3l; idx = i;
    } else if (t < 14592) {               // biases
        int i = t - 14336;
        if (i < 64) {
            float s = g1[i] * rsqrtf(v1[i] + EPS);
            b1f[i] = (b1[i] - m1[i]) * s + be1[i];
        } else if (i < 128) {
            int j = i - 64;
            float s = g2[j] * rsqrtf(v2[j] + EPS);
            b2f[j] = (b2[j] - m2[j]) * s + be2[j];
        } else {
            int j = i - 128;
            float s = g3[j] * rsqrtf(v3[j] + EPS);
            b3f[j] = (b3[j] - m3[j]) * s + be3[j];
        }
        return;
    } else return;
    unsigned hi = rne_bf16(val);
    unsigned lo = rne_bf16(val - __uint_as_float(hi << 16));
    ph[idx] = (u16)hi;
    pl[idx] = (u16)lo;
}

// cursor = 1 (self loop) and out = -inf in one pass
__global__ void init_kernel(int* __restrict__ cursor, uint4* __restrict__ out4) {
    int i = blockIdx.x * 256 + threadIdx.x;
    if (i < N_NODES) cursor[i] = 1;
    if (i < (N_NODES * 128) / 4)
        out4[i] = make_uint4(0xFF800000u, 0xFF800000u, 0xFF800000u, 0xFF800000u);
}

__global__ void hist_kernel(const int* __restrict__ ei, int* __restrict__ cursor) {
    int e = blockIdx.x * 256 + threadIdx.x;
    if (e < N_EDGES) atomicAdd(&cursor[ei[N_EDGES + e]], 1);
}

// multi-block scan: A) per-block exclusive scan + block sums
__global__ void scanA_kernel(int* __restrict__ cursor, int* __restrict__ bsum) {
    __shared__ int sh[256];
    const int tid = threadIdx.x;
    int i = blockIdx.x * 256 + tid;
    int c = (i < N_NODES) ? cursor[i] : 0;
    sh[tid] = c;
    __syncthreads();
    int v = c;
    for (int off = 1; off < 256; off <<= 1) {
        int t = (tid >= off) ? sh[tid - off] : 0;
        __syncthreads();
        v += t;
        sh[tid] = v;
        __syncthreads();
    }
    if (i < N_NODES) cursor[i] = v - c;           // exclusive within block
    if (tid == 255) bsum[blockIdx.x] = v;         // block total
}

// B) exclusive scan of the block sums
__global__ void scanB_kernel(int* __restrict__ bsum) {
    __shared__ int sh[256];
    const int tid = threadIdx.x;
    int c = (tid < SCAN_NB) ? bsum[tid] : 0;
    sh[tid] = c;
    __syncthreads();
    int v = c;
    for (int off = 1; off < 256; off <<= 1) {
        int t = (tid >= off) ? sh[tid - off] : 0;
        __syncthreads();
        v += t;
        sh[tid] = v;
        __syncthreads();
    }
    if (tid < SCAN_NB) bsum[tid] = v - c;
}

// C) add block offsets
__global__ void scanC_kernel(int* __restrict__ cursor, const int* __restrict__ bsum) {
    int i = blockIdx.x * 256 + threadIdx.x;
    if (i < N_NODES) cursor[i] += bsum[blockIdx.x];
}

__global__ void scatter_kernel(const int* __restrict__ ei, int* __restrict__ cursor,
                               int* __restrict__ eid) {
    int e = blockIdx.x * 256 + threadIdx.x;
    if (e >= TOT_E) return;
    int d = (e < N_EDGES) ? ei[N_EDGES + e] : (e - N_EDGES);
    int p = atomicAdd(&cursor[d], 1);
    eid[p] = e;
}

// 1 wave/block, 64 edges/wave (r6 structure), hi/lo bf16 LDS planes (8KB+8KB),
// XOR swizzle byte^=((row&7)<<4), bpermute F-frags, barrier-free LDS reuse
// (per-wave in-order DS pipe).
__global__ __launch_bounds__(64, 2) void gather_kernel(
    const float* __restrict__ x, const float* __restrict__ pos,
    const int* __restrict__ ei, const int* __restrict__ eid,
    const u16* __restrict__ w1h, const u16* __restrict__ w1l,
    const u16* __restrict__ w2h, const u16* __restrict__ w2l,
    const u16* __restrict__ w3h, const u16* __restrict__ w3l,
    const float* __restrict__ b1f, const float* __restrict__ b2f,
    const float* __restrict__ b3f, float* __restrict__ out)
{
    __shared__ char smem[16384];

    const int lane = threadIdx.x;
    const int l15 = lane & 15, g = lane >> 4;
    const int e = blockIdx.x * 64 + lane;
    const bool active = e < TOT_E;

    int src = 0, dst = 0;
    if (active) {
        int id = eid[e];
        if (id < N_EDGES) { src = ei[id]; dst = ei[N_EDGES + id]; }
        else              { src = dst = id - N_EDGES; }
    }
    const int nid = active ? dst : (-1 - lane);   // unique negatives in tail

    // full-exec-mask shuffles only (round-4 lesson)
    const int np1 = __shfl_down(nid, 1);
    const bool seg_last = (lane == 63) || (np1 != nid);
    const unsigned long long segmask = __ballot(seg_last);

    float f0 = x[src * 3 + 0];
    float f1 = x[src * 3 + 1];
    float f2 = x[src * 3 + 2];
    float f3 = pos[src * 3 + 0] - pos[dst * 3 + 0];
    float f4 = pos[src * 3 + 1] - pos[dst * 3 + 1];
    float f5 = pos[src * 3 + 2] - pos[dst * 3 + 2];

    // pack f hi/lo pairs: u*0 = [k0|k1], u*1 = [k2|k3], u*2 = [k4|k5]
    unsigned h0 = rne_bf16(f0), h1 = rne_bf16(f1), h2 = rne_bf16(f2);
    unsigned h3 = rne_bf16(f3), h4 = rne_bf16(f4), h5 = rne_bf16(f5);
    unsigned l0 = rne_bf16(f0 - __uint_as_float(h0 << 16));
    unsigned l1 = rne_bf16(f1 - __uint_as_float(h1 << 16));
    unsigned l2 = rne_bf16(f2 - __uint_as_float(h2 << 16));
    unsigned l3 = rne_bf16(f3 - __uint_as_float(h3 << 16));
    unsigned l4 = rne_bf16(f4 - __uint_as_float(h4 << 16));
    unsigned l5 = rne_bf16(f5 - __uint_as_float(h5 << 16));
    unsigned uh0 = h0 | (h1 << 16), uh1 = h2 | (h3 << 16), uh2 = h4 | (h5 << 16);
    unsigned ul0 = l0 | (l1 << 16), ul1 = l2 | (l3 << 16), ul2 = l4 | (l5 << 16);

    // L1 A-frags via bpermute (edge 16tm+l15's features; g>0 lanes are k>=8 -> 0)
    v8s a1h[4], a1l[4];
#pragma unroll
    for (int tm = 0; tm < 4; ++tm) {
        int bidx = (16 * tm + l15) * 4;
        unsigned p0 = (unsigned)__builtin_amdgcn_ds_bpermute(bidx, (int)uh0);
        unsigned p1 = (unsigned)__builtin_amdgcn_ds_bpermute(bidx, (int)uh1);
        unsigned p2 = (unsigned)__builtin_amdgcn_ds_bpermute(bidx, (int)uh2);
        unsigned q0 = (unsigned)__builtin_amdgcn_ds_bpermute(bidx, (int)ul0);
        unsigned q1 = (unsigned)__builtin_amdgcn_ds_bpermute(bidx, (int)ul1);
        unsigned q2 = (unsigned)__builtin_amdgcn_ds_bpermute(bidx, (int)ul2);
        if (g != 0) { p0 = p1 = p2 = q0 = q1 = q2 = 0u; }
        uint4 th = make_uint4(p0, p1, p2, 0u);
        uint4 tl = make_uint4(q0, q1, q2, 0u);
        a1h[tm] = __builtin_bit_cast(v8s, th);
        a1l[tm] = __builtin_bit_cast(v8s, tl);
    }

    // ---- layer 1: full 4x4 acc (this wave owns all 64 output features)
    v4f acc[4][4];
#pragma unroll
    for (int tn = 0; tn < 4; ++tn) {
        float bv = b1f[16 * tn + l15];
#pragma unroll
        for (int tm = 0; tm < 4; ++tm) acc[tm][tn] = (v4f){bv, bv, bv, bv};
    }
#pragma unroll
    for (int tn = 0; tn < 4; ++tn) {
        v8s bh = *(const v8s*)&w1h[(16 * tn + l15) * 32 + g * 8];
        v8s bl = *(const v8s*)&w1l[(16 * tn + l15) * 32 + g * 8];
#pragma unroll
        for (int tm = 0; tm < 4; ++tm) { MFMA3(acc[tm][tn], a1h[tm], a1l[tm], bh, bl) }
    }
    // relu + split + write H1 planes (hi @0, lo @8192), swizzled
#pragma unroll
    for (int tm = 0; tm < 4; ++tm)
#pragma unroll
        for (int tn = 0; tn < 4; ++tn)
#pragma unroll
            for (int r = 0; r < 4; ++r) {
                int row = 16 * tm + 4 * g + r, col = 16 * tn + l15;
                float v = fmaxf(acc[tm][tn][r], 0.f);
                unsigned hi = rne_bf16(v);
                unsigned lo = rne_bf16(v - __uint_as_float(hi << 16));
                int off = row * 128 + ((col * 2) ^ ((row & 7) << 4));
                *(u16*)(smem + off) = (u16)hi;
                *(u16*)(smem + 8192 + off) = (u16)lo;
            }

    // ---- read H1 A-frags (in-order DS pipe: no barrier needed, 1 wave)
    v8s ah[4][2], al[4][2];
#pragma unroll
    for (int tm = 0; tm < 4; ++tm)
#pragma unroll
        for (int tk = 0; tk < 2; ++tk) {
            int row = 16 * tm + l15;
            int off = row * 128 + ((tk * 64 + g * 16) ^ ((row & 7) << 4));
            ah[tm][tk] = *(const v8s*)(smem + off);
            al[tm][tk] = *(const v8s*)(smem + 8192 + off);
        }

    // ---- layer 2
#pragma unroll
    for (int tn = 0; tn < 4; ++tn) {
        float bv = b2f[16 * tn + l15];
#pragma unroll
        for (int tm = 0; tm < 4; ++tm) acc[tm][tn] = (v4f){bv, bv, bv, bv};
    }
#pragma unroll
    for (int tn = 0; tn < 4; ++tn)
#pragma unroll
        for (int tk = 0; tk < 2; ++tk) {
            v8s bh = *(const v8s*)&w2h[(16 * tn + l15) * 64 + tk * 32 + g * 8];
            v8s bl = *(const v8s*)&w2l[(16 * tn + l15) * 64 + tk * 32 + g * 8];
#pragma unroll
            for (int tm = 0; tm < 4; ++tm) { MFMA3(acc[tm][tn], ah[tm][tk], al[tm][tk], bh, bl) }
        }
    // relu + split + write H2 planes
#pragma unroll
    for (int tm = 0; tm < 4; ++tm)
#pragma unroll
        for (int tn = 0; tn < 4; ++tn)
#pragma unroll
            for (int r = 0; r < 4; ++r) {
                int row = 16 * tm + 4 * g + r, col = 16 * tn + l15;
                float v = fmaxf(acc[tm][tn][r], 0.f);
                unsigned hi = rne_bf16(v);
                unsigned lo = rne_bf16(v - __uint_as_float(hi << 16));
                int off = row * 128 + ((col * 2) ^ ((row & 7) << 4));
                *(u16*)(smem + off) = (u16)hi;
                *(u16*)(smem + 8192 + off) = (u16)lo;
            }

    // ---- read H2 A-frags
#pragma unroll
    for (int tm = 0; tm < 4; ++tm)
#pragma unroll
        for (int tk = 0; tk < 2; ++tk) {
            int row = 16 * tm + l15;
            int off = row * 128 + ((tk * 64 + g * 16) ^ ((row & 7) << 4));
            ah[tm][tk] = *(const v8s*)(smem + off);
            al[tm][tk] = *(const v8s*)(smem + 8192 + off);
        }

    // ---- layer 3: two 64-col halves; f32 stage reuses the full 16KB
#pragma unroll
    for (int h = 0; h < 2; ++h) {
#pragma unroll
        for (int tn = 0; tn < 4; ++tn) {
            float bv = b3f[64 * h + 16 * tn + l15];
#pragma unroll
            for (int tm = 0; tm < 4; ++tm) acc[tm][tn] = (v4f){bv, bv, bv, bv};
        }
#pragma unroll
        for (int tn = 0; tn < 4; ++tn)
#pragma unroll
            for (int tk = 0; tk < 2; ++tk) {
                int nrow = 16 * (4 * h + tn) + l15;
                v8s bh = *(const v8s*)&w3h[nrow * 64 + tk * 32 + g * 8];
                v8s bl = *(const v8s*)&w3l[nrow * 64 + tk * 32 + g * 8];
#pragma unroll
                for (int tm = 0; tm < 4; ++tm) { MFMA3(acc[tm][tn], ah[tm][tk], al[tm][tk], bh, bl) }
            }
        // stage f32 [64 edge][64 col], rows 256B, swizzled
#pragma unroll
        for (int tm = 0; tm < 4; ++tm)
#pragma unroll
            for (int tn = 0; tn < 4; ++tn)
#pragma unroll
                for (int r = 0; r < 4; ++r) {
                    int row = 16 * tm + 4 * g + r, col = 16 * tn + l15;
                    int off = row * 256 + ((col * 4) ^ ((row & 7) << 4));
                    *(float*)(smem + off) = acc[tm][tn][r];
                }

        // serial uniform epilogue: lane = feature (h*64+lane); walk 64 edges
        {
            float runmax = -__builtin_inff();
            bool first = true;
#pragma unroll
            for (int e2 = 0; e2 < 64; ++e2) {
                int off = e2 * 256 + ((lane * 4) ^ ((e2 & 7) << 4));
                float val = *(const float*)(smem + off);
                runmax = fmaxf(runmax, val);
                if ((segmask >> e2) & 1ull) {
                    int n = __builtin_amdgcn_readlane(nid, e2);
                    if (n >= 0) {
                        float* op = out + (size_t)n * 128 + h * 64 + lane;
                        // first/last segment may span block boundaries
                        if (first || e2 == 63) atomicMax(op, runmax);
                        else *op = runmax;
                    }
                    first = false;
                    runmax = -__builtin_inff();
                }
            }
        }
    }
}

extern "C" void kernel_launch(void* const* d_in, const int* in_sizes, int n_in,
                              void* d_out, int out_size, void* d_ws, size_t ws_size,
                              hipStream_t stream) {
    const float* x   = (const float*)d_in[0];
    const float* pos = (const float*)d_in[1];
    const float* W1  = (const float*)d_in[2];
    const float* b1  = (const float*)d_in[3];
    const float* g1  = (const float*)d_in[4];
    const float* be1 = (const float*)d_in[5];
    const float* m1  = (const float*)d_in[6];
    const float* v1  = (const float*)d_in[7];
    const float* W2  = (const float*)d_in[8];
    const float* b2  = (const float*)d_in[9];
    const float* g2  = (const float*)d_in[10];
    const float* be2 = (const float*)d_in[11];
    const float* m2  = (const float*)d_in[12];
    const float* v2  = (const float*)d_in[13];
    const float* W3  = (const float*)d_in[14];
    const float* b3  = (const float*)d_in[15];
    const float* g3  = (const float*)d_in[16];
    const float* be3 = (const float*)d_in[17];
    const float* m3  = (const float*)d_in[18];
    const float* v3  = (const float*)d_in[19];
    const int*   ei  = (const int*)d_in[20];

    char* ws = (char*)d_ws;
    u16* w1h = (u16*)(ws + WS_W1H);
    u16* w1l = (u16*)(ws + WS_W1L);
    u16* w2h = (u16*)(ws + WS_W2H);
    u16* w2l = (u16*)(ws + WS_W2L);
    u16* w3h = (u16*)(ws + WS_W3H);
    u16* w3l = (u16*)(ws + WS_W3L);
    float* b1f = (float*)(ws + WS_B1F);
    float* b2f = (float*)(ws + WS_B2F);
    float* b3f = (float*)(ws + WS_B3F);
    int* bsum   = (int*)(ws + WS_BSUM);
    int* cursor = (int*)(ws + WS_CURSOR);
    int* eid    = (int*)(ws + WS_EID);
    float* outf = (float*)d_out;

    fold_kernel<<<57, 256, 0, stream>>>(
        W1, b1, g1, be1, m1, v1, W2, b2, g2, be2, m2, v2,
        W3, b3, g3, be3, m3, v3, w1h, w1l, w2h, w2l, w3h, w3l, b1f, b2f, b3f);

    init_kernel<<<(N_NODES * 128 / 4 + 255) / 256, 256, 0, stream>>>(
        cursor, (uint4*)d_out);

    hist_kernel<<<(N_EDGES + 255) / 256, 256, 0, stream>>>(ei, cursor);
    scanA_kernel<<<SCAN_NB, 256, 0, stream>>>(cursor, bsum);
    scanB_kernel<<<1, 256, 0, stream>>>(bsum);
    scanC_kernel<<<SCAN_NB, 256, 0, stream>>>(cursor, bsum);
    scatter_kernel<<<(TOT_E + 255) / 256, 256, 0, stream>>>(ei, cursor, eid);

    gather_kernel<<<(TOT_E + 63) / 64, 64, 0, stream>>>(
        x, pos, ei, eid, w1h, w1l, w2h, w2l, w3h, w3l, b1f, b2f, b3f, outf);
}